// Round 10
// baseline (112.880 us; speedup 1.0000x reference)
//
#include <hip/hip_runtime.h>
#include <hip/hip_bf16.h>
#include <stdint.h>

#define CIN   512
#define COUT  512
#define BM    128
#define BN    128
#define NIB   16            // 512/32 i-blocks
#define KSTEPS 128          // NIB * 8 degrees (d=1..8); d=0 folded into bias

typedef float f32x4 __attribute__((ext_vector_type(4)));
typedef short s16x8 __attribute__((ext_vector_type(8)));

// Frag-packed bf16 weights: [ks(128)][cg(32)][lane(64)] of 8 bf16 (16B)
__device__ uint4 Wp_g[KSTEPS * 32 * 64];   // 4 MB
__device__ float bias_g[COUT];

__device__ __forceinline__ uint32_t cvtpk(float lo, float hi) {
  uint32_t r;
  asm("v_cvt_pk_bf16_f32 %0, %1, %2" : "=v"(r) : "v"(lo), "v"(hi));
  return r;  // low 16 = bf16(lo), high 16 = bf16(hi)
}

__device__ __forceinline__ float ftanh(float v) {
  float e = __expf(v + v);
  return 1.0f - __fdividef(2.0f, e + 1.0f);
}

// LDS-visibility barrier that does NOT drain vmcnt (B prefetch stays in flight).
__device__ __forceinline__ void lds_barrier() {
  asm volatile("s_waitcnt lgkmcnt(0)" ::: "memory");
  __builtin_amdgcn_s_barrier();
  asm volatile("" ::: "memory");
}

// ---- pack weights into MFMA B-fragment order, bf16 (round-2 verified) ----
__global__ void pack_w(const float* __restrict__ cw) {
  __shared__ float lf[32 * 144];
  int ib = blockIdx.x >> 5;
  int cg = blockIdx.x & 31;
  for (int r = threadIdx.x; r < 32 * 144; r += 256) {
    int il = r / 144;
    int rem = r - il * 144;
    lf[r] = cw[(size_t)(ib * 32 + il) * (COUT * 9) + cg * 144 + rem];
  }
  __syncthreads();
  for (int v = threadIdx.x; v < 512; v += 256) {
    int ksl = v >> 6;            // d-1
    int lane = v & 63;
    int d = ksl + 1;
    int lh = lane >> 4, l15 = lane & 15;
    uint32_t p[4];
    #pragma unroll
    for (int q = 0; q < 4; ++q) {
      float a = lf[(lh * 8 + 2 * q    ) * 144 + l15 * 9 + d];
      float b = lf[(lh * 8 + 2 * q + 1) * 144 + l15 * 9 + d];
      p[q] = cvtpk(a, b);
    }
    Wp_g[((ib * 8 + ksl) * 32 + cg) * 64 + lane] = make_uint4(p[0], p[1], p[2], p[3]);
  }
}

// ---- bias[o] = sum_i C[i][o][0] (d=0 / T_0==1 term): one block per o ----
__global__ void bias_k(const float* __restrict__ cw) {
  int o = blockIdx.x;
  int t = threadIdx.x;
  float s = 0.f;
  #pragma unroll
  for (int q = 0; q < 8; ++q)
    s += cw[(size_t)(t + 64 * q) * (COUT * 9) + o * 9];
  #pragma unroll
  for (int off = 32; off; off >>= 1) s += __shfl_down(s, off);
  if (t == 0) bias_g[o] = s;
}

// ---- fused basis-generation + GEMM, cross-block anti-phase ----
// 128x128 tile, 4 waves (2x2 grid of 64x64), grid=512 -> 2 INDEPENDENT
// blocks/CU, one wave of each block per SIMD. When one block stalls at its
// (lgkm-only) barrier, the sibling block's wave keeps the MFMA pipe busy.
// All data mappings verbatim from the round-2-verified kernel; each thread
// runs 16 Chebyshev chains (2 contiguous uint4 emits, conflict-free).
__global__ void __launch_bounds__(256, 2) cheby_gemm(const float* __restrict__ x,
                                                     float* __restrict__ out) {
  __shared__ uint4 lds[2 * 4 * 4 * BM];   // [buf][slot(4 d)][h(4)][row(128)] = 64 KB
  const int tid  = threadIdx.x;
  const int lane = tid & 63;
  const int l15  = lane & 15;
  const int lh   = lane >> 4;
  const int w    = tid >> 6;        // 0..3
  const int wr   = w >> 1;          // 2 row-groups of 64
  const int wc   = w & 1;           // 2 col-groups of 64

  // bijective XCD swizzle (512 blocks, 512 % 8 == 0)
  int b0  = blockIdx.x;
  int bid = (b0 & 7) * 64 + (b0 >> 3);
  const int rb  = (bid >> 2) * BM;
  const int cb  = bid & 3;
  const int ocb = cb * BN;
  const int cgbase = cb * 8 + wc * 4;

  // generator mapping: 16 chains/thread (2 i-chunks of 8), contiguous emits
  const int c0   = wr * 2;                 // i-chunk base (0 or 2)
  const int grow = wc * 64 + lane;         // row (0..127)
  const float* xrow = x + (size_t)(rb + grow) * CIN + c0 * 8;

  // B pointer hoist (round-2 verified addressing)
  const uint4* pB = Wp_g + (size_t)cgbase * 64 + lane;

  // accumulators, initialized with the d=0 bias term
  f32x4 acc[4][4];
  #pragma unroll
  for (int cf = 0; cf < 4; ++cf) {
    float bv = bias_g[ocb + wc * 64 + cf * 16 + l15];
    #pragma unroll
    for (int rf = 0; rf < 4; ++rf) {
      acc[rf][cf][0] = bv; acc[rf][cf][1] = bv;
      acc[rf][cf][2] = bv; acc[rf][cf][3] = bv;
    }
  }

  float xv[16], u2[16], tm1[16], tm2[16];

  auto loadX = [&](int ib) {
    const float4* p = reinterpret_cast<const float4*>(xrow + ib * 32);
    #pragma unroll
    for (int q = 0; q < 4; ++q) {
      float4 v = p[q];
      xv[4*q+0] = v.x; xv[4*q+1] = v.y; xv[4*q+2] = v.z; xv[4*q+3] = v.w;
    }
  };
  auto compute_u = [&]() {
    #pragma unroll
    for (int k = 0; k < 16; ++k) {
      float u = ftanh(ftanh(xv[k]));
      tm1[k] = u; tm2[k] = 1.0f; u2[k] = u + u;
    }
  };
  auto advance = [&]() {
    #pragma unroll
    for (int k = 0; k < 16; ++k) {
      float t = __builtin_fmaf(u2[k], tm1[k], -tm2[k]);
      tm2[k] = tm1[k]; tm1[k] = t;
    }
  };
  auto emit = [&](int buf, int slot) {   // write current tm1[] (= T_d) as bf16
    uint32_t q0 = cvtpk(tm1[0],  tm1[1]),  q1 = cvtpk(tm1[2],  tm1[3]);
    uint32_t q2 = cvtpk(tm1[4],  tm1[5]),  q3 = cvtpk(tm1[6],  tm1[7]);
    uint32_t q4 = cvtpk(tm1[8],  tm1[9]),  q5 = cvtpk(tm1[10], tm1[11]);
    uint32_t q6 = cvtpk(tm1[12], tm1[13]), q7 = cvtpk(tm1[14], tm1[15]);
    int base = (buf * 4 + slot) * 4;
    lds[(base + c0    ) * BM + grow] = make_uint4(q0, q1, q2, q3);
    lds[(base + c0 + 1) * BM + grow] = make_uint4(q4, q5, q6, q7);
  };

  s16x8 breg[2][4];                 // [parity][cf]
  auto loadB = [&](int par, int ks) {
    #pragma unroll
    for (int cf = 0; cf < 4; ++cf) {
      uint4 v = pB[(size_t)ks * 2048 + cf * 64];
      breg[par][cf] = __builtin_bit_cast(s16x8, v);
    }
  };
  auto mfma_step = [&](int buf, int slot, int par) {
    s16x8 a[4];
    int base = ((buf * 4 + slot) * 4 + lh) * BM + wr * 64 + l15;
    #pragma unroll
    for (int rf = 0; rf < 4; ++rf)
      a[rf] = *reinterpret_cast<const s16x8*>(&lds[base + rf * 16]);
    __builtin_amdgcn_s_setprio(1);
    #pragma unroll
    for (int rf = 0; rf < 4; ++rf) {
      #pragma unroll
      for (int cf = 0; cf < 4; ++cf)
        acc[rf][cf] = __builtin_amdgcn_mfma_f32_16x16x32_bf16(
            a[rf], breg[par][cf], acc[rf][cf], 0, 0, 0);
    }
    __builtin_amdgcn_s_setprio(0);
  };

  // ---- prologue: generate (ib=0, d=1..4) into buf0 ----
  loadX(0);
  compute_u();
  emit(0, 0);                 // d=1 : T_1 = u
  advance(); emit(0, 1);      // d=2
  advance(); emit(0, 2);      // d=3
  advance(); emit(0, 3);      // d=4
  loadB(0, 0);
  lds_barrier();

  for (int ib = 0; ib < NIB; ++ib) {
    if (ib + 1 < NIB) loadX(ib + 1);   // consumed at PART1 j=0 (compute_u)

    // PART 0: consume buf0 (d=1..4); generate (ib, d=5..8) -> buf1
    #pragma unroll
    for (int j = 0; j < 4; ++j) {
      int ks = ib * 8 + j;
      loadB((j + 1) & 1, ks + 1);          // ks+1 <= 124 always here
      mfma_step(0, j, j & 1);
      advance(); emit(1, j);               // d = 5+j
    }
    lds_barrier();

    // PART 1: consume buf1 (d=5..8); generate (ib+1, d=1..4) -> buf0
    #pragma unroll
    for (int j = 0; j < 4; ++j) {
      int ks = ib * 8 + 4 + j;
      if (ks + 1 < KSTEPS) loadB((j + 1) & 1, ks + 1);
      mfma_step(1, j, j & 1);
      if (ib + 1 < NIB) {
        if (j == 0) { compute_u(); emit(0, 0); }
        else        { advance();   emit(0, j); }
      }
    }
    lds_barrier();
  }

  // ---- epilogue: C/D layout col = lane&15, row = (lane>>4)*4 + reg ----
  const int orow = rb + wr * 64 + lh * 4;
  const int ocol = ocb + wc * 64 + l15;
  #pragma unroll
  for (int rf = 0; rf < 4; ++rf) {
    #pragma unroll
    for (int cf = 0; cf < 4; ++cf) {
      #pragma unroll
      for (int r = 0; r < 4; ++r)
        out[(size_t)(orow + rf * 16 + r) * COUT + ocol + cf * 16] = acc[rf][cf][r];
    }
  }
}

extern "C" void kernel_launch(void* const* d_in, const int* in_sizes, int n_in,
                              void* d_out, int out_size, void* d_ws, size_t ws_size,
                              hipStream_t stream) {
  const float* x  = (const float*)d_in[0];   // (16384, 512) fp32
  const float* cw = (const float*)d_in[1];   // (512, 512, 9) fp32
  float* out = (float*)d_out;                // (16384, 512) fp32

  pack_w<<<dim3(512), dim3(256), 0, stream>>>(cw);
  bias_k<<<dim3(COUT), dim3(64), 0, stream>>>(cw);
  cheby_gemm<<<dim3(512), dim3(256), 0, stream>>>(x, out);
}